// Round 1
// baseline (638.626 us; speedup 1.0000x reference)
//
#include <hip/hip_runtime.h>
#include <hip/hip_bf16.h>

#define EMBED 1024
#define WINDOW 512
#define NROWS 16384  // 4 * 4096

typedef __attribute__((ext_vector_type(4))) float f32x4;
typedef __bf16 bf16x8 __attribute__((ext_vector_type(8)));

// ---------------- prep: fp32 -> bf16 cast, 8 elems/thread ----------------
__global__ __launch_bounds__(256) void cast_bf16_kernel(
    const float* __restrict__ in, __bf16* __restrict__ out, int n8) {
  int i = blockIdx.x * blockDim.x + threadIdx.x;
  if (i >= n8) return;
  const f32x4* p = (const f32x4*)(in + (size_t)i * 8);
  f32x4 a = p[0], b = p[1];
  bf16x8 o = {(__bf16)a[0], (__bf16)a[1], (__bf16)a[2], (__bf16)a[3],
              (__bf16)b[0], (__bf16)b[1], (__bf16)b[2], (__bf16)b[3]};
  *(bf16x8*)(out + (size_t)i * 8) = o;
}

// ---------------- prep: MB [512][1024] fp32 -> MB^T [1024][512] bf16 ------
__global__ __launch_bounds__(256) void transpose_mb_kernel(
    const float* __restrict__ mb, __bf16* __restrict__ mbt) {
  int idx = blockIdx.x * blockDim.x + threadIdx.x;  // over 512*1024
  int w = idx >> 10, d = idx & 1023;
  mbt[(size_t)d * WINDOW + w] = (__bf16)mb[idx];
}

// ---------------- scores + softmax -> attn (bf16) ------------------------
// grid: 256 blocks (64 rows each), 256 threads (4 waves, 16 rows/wave).
// Each wave: 1 m-tile x 32 n-tiles of 16x16x32 MFMA over K=1024.
__global__ __launch_bounds__(256) void scores_softmax_kernel(
    const float* __restrict__ x, const __bf16* __restrict__ mbb,
    __bf16* __restrict__ attn) {
  const int lane = threadIdx.x & 63;
  const int wave = threadIdx.x >> 6;
  const int row0 = blockIdx.x * 64 + wave * 16;
  const int fr = lane & 15;   // A row / B col / D col low index
  const int fq = lane >> 4;   // quad
  const int kb = fq * 8;      // k base within 32-wide k-tile

  f32x4 acc[32];
#pragma unroll
  for (int nt = 0; nt < 32; ++nt) acc[nt] = (f32x4){0.f, 0.f, 0.f, 0.f};

  for (int kt = 0; kt < 32; ++kt) {
    const int k0 = kt * 32 + kb;
    const float* xp = x + (size_t)(row0 + fr) * EMBED + k0;
    f32x4 xa = *(const f32x4*)xp;
    f32x4 xc = *(const f32x4*)(xp + 4);
    bf16x8 a = {(__bf16)xa[0], (__bf16)xa[1], (__bf16)xa[2], (__bf16)xa[3],
                (__bf16)xc[0], (__bf16)xc[1], (__bf16)xc[2], (__bf16)xc[3]};
    const __bf16* bp = mbb + (size_t)fr * EMBED + k0;
#pragma unroll
    for (int nt = 0; nt < 32; ++nt) {
      bf16x8 b = *(const bf16x8*)(bp + (size_t)nt * 16 * EMBED);
      acc[nt] = __builtin_amdgcn_mfma_f32_16x16x32_bf16(a, b, acc[nt], 0, 0, 0);
    }
  }

  // softmax over 512 cols per row; rows = row0 + fq*4 + j, col = fr + 16*nt
  const float scale = 0.03125f;  // 1/sqrt(1024)
  float mx[4] = {-1e30f, -1e30f, -1e30f, -1e30f};
#pragma unroll
  for (int nt = 0; nt < 32; ++nt)
#pragma unroll
    for (int j = 0; j < 4; ++j) {
      float v = acc[nt][j] * scale;
      acc[nt][j] = v;
      mx[j] = fmaxf(mx[j], v);
    }
#pragma unroll
  for (int j = 0; j < 4; ++j)
    for (int off = 1; off < 16; off <<= 1)
      mx[j] = fmaxf(mx[j], __shfl_xor(mx[j], off));

  float sm[4] = {0.f, 0.f, 0.f, 0.f};
#pragma unroll
  for (int nt = 0; nt < 32; ++nt)
#pragma unroll
    for (int j = 0; j < 4; ++j) {
      float e = __expf(acc[nt][j] - mx[j]);
      acc[nt][j] = e;
      sm[j] += e;
    }
#pragma unroll
  for (int j = 0; j < 4; ++j)
    for (int off = 1; off < 16; off <<= 1) sm[j] += __shfl_xor(sm[j], off);

  float inv[4];
#pragma unroll
  for (int j = 0; j < 4; ++j) inv[j] = 1.0f / sm[j];

  __bf16* ap = attn + (size_t)(row0 + fq * 4) * WINDOW + fr;
#pragma unroll
  for (int nt = 0; nt < 32; ++nt)
#pragma unroll
    for (int j = 0; j < 4; ++j)
      ap[(size_t)j * WINDOW + nt * 16] = (__bf16)(acc[nt][j] * inv[j]);
}

// ---------------- retrieved + gate + combine -> out ----------------------
// grid: 1024 blocks = 256 row-blocks x 4 col-chunks. 256 threads, 4 waves.
// Each wave: 16 rows x 256 cols. accr (K=512 over attn) + accg (K=1024).
__global__ __launch_bounds__(256) void out_kernel(
    const float* __restrict__ x, const __bf16* __restrict__ xb,
    const __bf16* __restrict__ attn, const __bf16* __restrict__ mbt,
    const __bf16* __restrict__ gwb, const float* __restrict__ gb,
    float* __restrict__ out) {
  const int lane = threadIdx.x & 63;
  const int wave = threadIdx.x >> 6;
  const int row0 = (blockIdx.x >> 2) * 64 + wave * 16;
  const int col0 = (blockIdx.x & 3) * 256;
  const int fr = lane & 15;
  const int fq = lane >> 4;
  const int kb = fq * 8;

  f32x4 accr[16], accg[16];
#pragma unroll
  for (int nt = 0; nt < 16; ++nt) {
    accr[nt] = (f32x4){0.f, 0.f, 0.f, 0.f};
    accg[nt] = (f32x4){0.f, 0.f, 0.f, 0.f};
  }

  // retrieved = attn @ MB : K = 512, B from MB^T [1024][512]
  for (int kt = 0; kt < 16; ++kt) {
    const int k0 = kt * 32 + kb;
    bf16x8 a = *(const bf16x8*)(attn + (size_t)(row0 + fr) * WINDOW + k0);
    const __bf16* bp = mbt + (size_t)(col0 + fr) * WINDOW + k0;
#pragma unroll
    for (int nt = 0; nt < 16; ++nt) {
      bf16x8 b = *(const bf16x8*)(bp + (size_t)nt * 16 * WINDOW);
      accr[nt] = __builtin_amdgcn_mfma_f32_16x16x32_bf16(a, b, accr[nt], 0, 0, 0);
    }
  }

  // gate_pre = x @ gate_w^T : K = 1024, B from gate_w [1024][1024] (row e, col d)
  for (int kt = 0; kt < 32; ++kt) {
    const int k0 = kt * 32 + kb;
    bf16x8 a = *(const bf16x8*)(xb + (size_t)(row0 + fr) * EMBED + k0);
    const __bf16* bp = gwb + (size_t)(col0 + fr) * EMBED + k0;
#pragma unroll
    for (int nt = 0; nt < 16; ++nt) {
      bf16x8 b = *(const bf16x8*)(bp + (size_t)nt * 16 * EMBED);
      accg[nt] = __builtin_amdgcn_mfma_f32_16x16x32_bf16(a, b, accg[nt], 0, 0, 0);
    }
  }

  // epilogue: out = g*x + (1-g)*retrieved, g = sigmoid(accg + bias)
#pragma unroll
  for (int nt = 0; nt < 16; ++nt) {
    const int col = col0 + nt * 16 + fr;
    const float bias = gb[col];
#pragma unroll
    for (int j = 0; j < 4; ++j) {
      const int row = row0 + fq * 4 + j;
      const float xv = x[(size_t)row * EMBED + col];
      const float t = accg[nt][j] + bias;
      const float g = 1.0f / (1.0f + __expf(-t));
      out[(size_t)row * EMBED + col] = g * xv + (1.0f - g) * accr[nt][j];
    }
  }
}

extern "C" void kernel_launch(void* const* d_in, const int* in_sizes, int n_in,
                              void* d_out, int out_size, void* d_ws,
                              size_t ws_size, hipStream_t stream) {
  const float* x = (const float*)d_in[0];
  const float* mb = (const float*)d_in[1];
  const float* gw = (const float*)d_in[2];
  const float* gb = (const float*)d_in[3];
  float* out = (float*)d_out;

  char* ws = (char*)d_ws;
  __bf16* xb = (__bf16*)(ws);                   // 16384*1024*2 = 33,554,432
  __bf16* mbb = (__bf16*)(ws + 33554432);       // 512*1024*2  =  1,048,576
  __bf16* mbt = (__bf16*)(ws + 34603008);       // 1024*512*2  =  1,048,576
  __bf16* gwb = (__bf16*)(ws + 35651584);       // 1024*1024*2 =  2,097,152
  __bf16* attn = (__bf16*)(ws + 37748736);      // 16384*512*2 = 16,777,216

  cast_bf16_kernel<<<8192, 256, 0, stream>>>(x, xb, 2097152);
  cast_bf16_kernel<<<256, 256, 0, stream>>>(mb, mbb, 65536);
  cast_bf16_kernel<<<512, 256, 0, stream>>>(gw, gwb, 131072);
  transpose_mb_kernel<<<2048, 256, 0, stream>>>(mb, mbt);
  scores_softmax_kernel<<<256, 256, 0, stream>>>(x, mbb, attn);
  out_kernel<<<1024, 256, 0, stream>>>(x, xb, attn, mbt, gwb, gb, out);
}

// Round 2
// 150.372 us; speedup vs baseline: 4.2470x; 4.2470x over previous
//
#include <hip/hip_runtime.h>
#include <hip/hip_bf16.h>

#define EMBED 1024
#define WINDOW 512
#define NROWS 16384  // 4 * 4096

typedef __attribute__((ext_vector_type(4))) float f32x4;
typedef __bf16 bf16x8 __attribute__((ext_vector_type(8)));

#define GLDS(g, l)                                                        \
  __builtin_amdgcn_global_load_lds(                                       \
      (const __attribute__((address_space(1))) void*)(const void*)(g),    \
      (__attribute__((address_space(3))) void*)(void*)(l), 16, 0, 0)

// ---------------- prep: fp32 -> bf16 cast, 8 elems/thread ----------------
__global__ __launch_bounds__(256) void cast_bf16_kernel(
    const float* __restrict__ in, __bf16* __restrict__ out, int n8) {
  int i = blockIdx.x * blockDim.x + threadIdx.x;
  if (i >= n8) return;
  const f32x4* p = (const f32x4*)(in + (size_t)i * 8);
  f32x4 a = p[0], b = p[1];
  bf16x8 o = {(__bf16)a[0], (__bf16)a[1], (__bf16)a[2], (__bf16)a[3],
              (__bf16)b[0], (__bf16)b[1], (__bf16)b[2], (__bf16)b[3]};
  *(bf16x8*)(out + (size_t)i * 8) = o;
}

// ---------------- prep: MB [512][1024] fp32 -> MB^T [1024][512] bf16 ------
__global__ __launch_bounds__(256) void transpose_mb_kernel(
    const float* __restrict__ mb, __bf16* __restrict__ mbt) {
  int idx = blockIdx.x * blockDim.x + threadIdx.x;  // over 512*1024
  int w = idx >> 10, d = idx & 1023;
  mbt[(size_t)d * WINDOW + w] = (__bf16)mb[idx];
}

// ---------------- GEMM1: S1[16384x512] = xb @ mbb^T, K=1024 --------------
// 128x128 tile, 256 threads (4 waves 2x2), BK=32, global_load_lds staging.
__global__ __launch_bounds__(256) void gemm_scores_kernel(
    const __bf16* __restrict__ xb, const __bf16* __restrict__ mbb,
    __bf16* __restrict__ s1) {
  __shared__ __bf16 Ash[128 * 32];
  __shared__ __bf16 Bsh[128 * 32];
  const int lane = threadIdx.x & 63;
  const int wave = threadIdx.x >> 6;
  const int bm = blockIdx.x >> 2;      // 128 row-blocks
  const int bn = blockIdx.x & 3;       // 4 col-blocks
  const int row0 = bm * 128;
  const int col0 = bn * 128;
  const int wr = (wave >> 1) * 64;
  const int wc = (wave & 1) * 64;
  const int fr = lane & 15;
  const int fq = lane >> 4;
  const int sub = lane >> 2;           // staging: row within 16
  const int ke = (lane & 3) * 8;       // staging: k elem base

  f32x4 acc[4][4];
#pragma unroll
  for (int m = 0; m < 4; ++m)
#pragma unroll
    for (int n = 0; n < 4; ++n) acc[m][n] = (f32x4){0.f, 0.f, 0.f, 0.f};

  for (int kt = 0; kt < 32; ++kt) {
    const int k0 = kt * 32;
#pragma unroll
    for (int i = 0; i < 2; ++i) {
      const int rb = wave * 32 + i * 16;  // row-chunk base (uniform per wave)
      GLDS(xb + (size_t)(row0 + rb + sub) * EMBED + k0 + ke, &Ash[rb * 32]);
      GLDS(mbb + (size_t)(col0 + rb + sub) * EMBED + k0 + ke, &Bsh[rb * 32]);
    }
    __syncthreads();
    bf16x8 ar[4], br[4];
#pragma unroll
    for (int m = 0; m < 4; ++m)
      ar[m] = *(const bf16x8*)&Ash[(wr + m * 16 + fr) * 32 + fq * 8];
#pragma unroll
    for (int n = 0; n < 4; ++n)
      br[n] = *(const bf16x8*)&Bsh[(wc + n * 16 + fr) * 32 + fq * 8];
#pragma unroll
    for (int m = 0; m < 4; ++m)
#pragma unroll
      for (int n = 0; n < 4; ++n)
        acc[m][n] =
            __builtin_amdgcn_mfma_f32_16x16x32_bf16(ar[m], br[n], acc[m][n], 0, 0, 0);
    __syncthreads();
  }

#pragma unroll
  for (int m = 0; m < 4; ++m)
#pragma unroll
    for (int n = 0; n < 4; ++n) {
      const int col = col0 + wc + n * 16 + fr;
#pragma unroll
      for (int j = 0; j < 4; ++j) {
        const int row = row0 + wr + m * 16 + fq * 4 + j;
        s1[(size_t)row * WINDOW + col] = (__bf16)acc[m][n][j];
      }
    }
}

// ---------------- softmax in-place on S1 rows (512 wide) -----------------
__global__ __launch_bounds__(256) void softmax_kernel(__bf16* __restrict__ s1) {
  const int row = blockIdx.x * 4 + (threadIdx.x >> 6);
  const int lane = threadIdx.x & 63;
  __bf16* p = s1 + (size_t)row * WINDOW + lane * 8;
  bf16x8 v = *(const bf16x8*)p;
  float f[8];
  float mx = -1e30f;
#pragma unroll
  for (int j = 0; j < 8; ++j) {
    f[j] = (float)v[j] * 0.03125f;  // 1/sqrt(1024)
    mx = fmaxf(mx, f[j]);
  }
#pragma unroll
  for (int off = 1; off < 64; off <<= 1) mx = fmaxf(mx, __shfl_xor(mx, off));
  float s = 0.f;
#pragma unroll
  for (int j = 0; j < 8; ++j) {
    f[j] = __expf(f[j] - mx);
    s += f[j];
  }
#pragma unroll
  for (int off = 1; off < 64; off <<= 1) s += __shfl_xor(s, off);
  const float inv = 1.0f / s;
  bf16x8 o;
#pragma unroll
  for (int j = 0; j < 8; ++j) o[j] = (__bf16)(f[j] * inv);
  *(bf16x8*)p = o;
}

// ---------------- dual GEMM + blend ---------------------------------------
// retrieved = attn(S1) @ MB (K=512, B tiles from mbt[1024][512])
// gate_pre  = xb @ gw^T   (K=1024, B tiles from gwb[1024][1024])
// out = g*x + (1-g)*retrieved, g = sigmoid(gate_pre + gb)
__global__ __launch_bounds__(256) void out_dual_kernel(
    const __bf16* __restrict__ attn, const __bf16* __restrict__ xb,
    const __bf16* __restrict__ mbt, const __bf16* __restrict__ gwb,
    const float* __restrict__ gb, float* __restrict__ out) {
  __shared__ __bf16 Ash[128 * 32];
  __shared__ __bf16 Bsh[128 * 32];
  const int lane = threadIdx.x & 63;
  const int wave = threadIdx.x >> 6;
  const int bm = blockIdx.x >> 3;      // 128 row-blocks
  const int bn = blockIdx.x & 7;       // 8 col-blocks
  const int row0 = bm * 128;
  const int col0 = bn * 128;
  const int wr = (wave >> 1) * 64;
  const int wc = (wave & 1) * 64;
  const int fr = lane & 15;
  const int fq = lane >> 4;
  const int sub = lane >> 2;
  const int ke = (lane & 3) * 8;

  f32x4 accr[4][4], accg[4][4];
#pragma unroll
  for (int m = 0; m < 4; ++m)
#pragma unroll
    for (int n = 0; n < 4; ++n) {
      accr[m][n] = (f32x4){0.f, 0.f, 0.f, 0.f};
      accg[m][n] = (f32x4){0.f, 0.f, 0.f, 0.f};
    }

  // Phase R: retrieved, K = 512
  for (int kt = 0; kt < 16; ++kt) {
    const int k0 = kt * 32;
#pragma unroll
    for (int i = 0; i < 2; ++i) {
      const int rb = wave * 32 + i * 16;
      GLDS(attn + (size_t)(row0 + rb + sub) * WINDOW + k0 + ke, &Ash[rb * 32]);
      GLDS(mbt + (size_t)(col0 + rb + sub) * WINDOW + k0 + ke, &Bsh[rb * 32]);
    }
    __syncthreads();
    bf16x8 ar[4], br[4];
#pragma unroll
    for (int m = 0; m < 4; ++m)
      ar[m] = *(const bf16x8*)&Ash[(wr + m * 16 + fr) * 32 + fq * 8];
#pragma unroll
    for (int n = 0; n < 4; ++n)
      br[n] = *(const bf16x8*)&Bsh[(wc + n * 16 + fr) * 32 + fq * 8];
#pragma unroll
    for (int m = 0; m < 4; ++m)
#pragma unroll
      for (int n = 0; n < 4; ++n)
        accr[m][n] =
            __builtin_amdgcn_mfma_f32_16x16x32_bf16(ar[m], br[n], accr[m][n], 0, 0, 0);
    __syncthreads();
  }

  // Phase G: gate_pre, K = 1024
  for (int kt = 0; kt < 32; ++kt) {
    const int k0 = kt * 32;
#pragma unroll
    for (int i = 0; i < 2; ++i) {
      const int rb = wave * 32 + i * 16;
      GLDS(xb + (size_t)(row0 + rb + sub) * EMBED + k0 + ke, &Ash[rb * 32]);
      GLDS(gwb + (size_t)(col0 + rb + sub) * EMBED + k0 + ke, &Bsh[rb * 32]);
    }
    __syncthreads();
    bf16x8 ar[4], br[4];
#pragma unroll
    for (int m = 0; m < 4; ++m)
      ar[m] = *(const bf16x8*)&Ash[(wr + m * 16 + fr) * 32 + fq * 8];
#pragma unroll
    for (int n = 0; n < 4; ++n)
      br[n] = *(const bf16x8*)&Bsh[(wc + n * 16 + fr) * 32 + fq * 8];
#pragma unroll
    for (int m = 0; m < 4; ++m)
#pragma unroll
      for (int n = 0; n < 4; ++n)
        accg[m][n] =
            __builtin_amdgcn_mfma_f32_16x16x32_bf16(ar[m], br[n], accg[m][n], 0, 0, 0);
    __syncthreads();
  }

  // Epilogue: sigmoid blend
#pragma unroll
  for (int m = 0; m < 4; ++m)
#pragma unroll
    for (int n = 0; n < 4; ++n) {
      const int col = col0 + wc + n * 16 + fr;
      const float bias = gb[col];
#pragma unroll
      for (int j = 0; j < 4; ++j) {
        const int row = row0 + wr + m * 16 + fq * 4 + j;
        const float xv = (float)xb[(size_t)row * EMBED + col];
        const float g = 1.0f / (1.0f + __expf(-(accg[m][n][j] + bias)));
        out[(size_t)row * EMBED + col] = g * xv + (1.0f - g) * accr[m][n][j];
      }
    }
}

extern "C" void kernel_launch(void* const* d_in, const int* in_sizes, int n_in,
                              void* d_out, int out_size, void* d_ws,
                              size_t ws_size, hipStream_t stream) {
  const float* x = (const float*)d_in[0];
  const float* mb = (const float*)d_in[1];
  const float* gw = (const float*)d_in[2];
  const float* gb = (const float*)d_in[3];
  float* out = (float*)d_out;

  char* ws = (char*)d_ws;
  __bf16* xb = (__bf16*)(ws);                   // 16384*1024*2 = 33,554,432
  __bf16* mbb = (__bf16*)(ws + 33554432);       // 512*1024*2  =  1,048,576
  __bf16* mbt = (__bf16*)(ws + 34603008);       // 1024*512*2  =  1,048,576
  __bf16* gwb = (__bf16*)(ws + 35651584);       // 1024*1024*2 =  2,097,152
  __bf16* s1 = (__bf16*)(ws + 37748736);        // 16384*512*2 = 16,777,216
  // total 54,525,952 bytes

  cast_bf16_kernel<<<8192, 256, 0, stream>>>(x, xb, 2097152);
  cast_bf16_kernel<<<256, 256, 0, stream>>>(mb, mbb, 65536);
  cast_bf16_kernel<<<512, 256, 0, stream>>>(gw, gwb, 131072);
  transpose_mb_kernel<<<2048, 256, 0, stream>>>(mb, mbt);
  gemm_scores_kernel<<<512, 256, 0, stream>>>(xb, mbb, s1);
  softmax_kernel<<<4096, 256, 0, stream>>>(s1);
  out_dual_kernel<<<1024, 256, 0, stream>>>(s1, xb, mbt, gwb, gb, out);
}